// Round 1
// baseline (357.826 us; speedup 1.0000x reference)
//
#include <hip/hip_runtime.h>

#define NC 32
#define NR 512
#define HC 16                 // components per half
#define NCHUNK 256            // one block per point-chunk
#define BLK 1024

// LDS: 3 axes * 512 rows * 16 comps fp32 + 16-float zero guard row
#define LDS_FLOATS (3 * NR * HC + HC)
#define LDS_BYTES (LDS_FLOATS * 4)

// ---------------------------------------------------------------------------
// Kernel 1: transpose the three [C=32, R=512] tables into half-split
// [h][R=512][16] layout in ws, so LDS staging is fully coalesced:
// dst[(c>>4)*8192 + r*16 + (c&15)] = src[c*512 + r]
// ---------------------------------------------------------------------------
__global__ __launch_bounds__(256) void transpose_vecs(
    const float* __restrict__ vx, const float* __restrict__ vy,
    const float* __restrict__ vz, float* __restrict__ tx,
    float* __restrict__ ty, float* __restrict__ tz) {
  int u = blockIdx.x * 256 + threadIdx.x;           // 0 .. 3*16384-1
  if (u >= 3 * NC * NR) return;
  int table = u >> 14;                              // /16384
  int e = u & (NC * NR - 1);                        // c*512 + r
  int c = e >> 9;
  int r = e & (NR - 1);
  const float* src = (table == 0) ? vx : (table == 1) ? vy : vz;
  float* dst = (table == 0) ? tx : (table == 1) ? ty : tz;
  dst[((c >> 4) << 13) + (r << 4) + (c & (HC - 1))] = src[e];
}

// ---------------------------------------------------------------------------
// In-LDS 1D lerp, 4 components. Inputs are guaranteed in [-1, 1) by the
// harness, so grid_sample zero-padding never triggers; we only clamp ix to
// [0, 511] for FP safety. When i0 == 511, w == 0 exactly, so the +16-row
// read (guard row for axis z, next-axis data for x/y -- finite) contributes 0.
// ---------------------------------------------------------------------------
__device__ __forceinline__ float4 lerp4(const float* __restrict__ t,
                                        float x, int j4) {
  float ix = fmaf(x, 0.5f * (NR - 1), 0.5f * (NR - 1));
  ix = fminf(fmaxf(ix, 0.0f), (float)(NR - 1));
  float f = floorf(ix);
  float w = ix - f;
  int i0 = (int)f;
  const float* a = t + (i0 << 4) + j4;
  float4 v0 = *(const float4*)a;
  float4 v1 = *(const float4*)(a + HC);             // row i0+1 = +64 B
  float4 r;
  r.x = fmaf(w, v1.x - v0.x, v0.x);
  r.y = fmaf(w, v1.y - v0.y, v0.y);
  r.z = fmaf(w, v1.z - v0.z, v0.z);
  r.w = fmaf(w, v1.w - v0.w, v0.w);
  return r;
}

// ---------------------------------------------------------------------------
// Kernel 2: one 1024-thread block owns a chunk of points. Two passes:
//   h=0: stage comps 0-15 of all 3 axes into LDS (96 KiB), compute, store
//   h=1: restage comps 16-31, compute, store
// 4 threads per point (4 comps each). All table reads are ds_read_b128;
// stores are 64-B-aligned complete 64-B chunks (HBM burst granularity),
// both halves of each 128-B out line written by the same block (L2 merge).
// ---------------------------------------------------------------------------
__global__ __launch_bounds__(BLK) void cp_encode_lds(
    const float* __restrict__ pos, const float* __restrict__ tx,
    const float* __restrict__ ty, const float* __restrict__ tz,
    float* __restrict__ out, int npts, int chunk_pts) {
  extern __shared__ float lds[];
  int tid = threadIdx.x;
  int base_p = blockIdx.x * chunk_pts;
  int pend = min(base_p + chunk_pts, npts);
  int iters = (chunk_pts + (BLK / 4) - 1) >> 8;     // points per iter = 256

  int j4 = (tid & 3) << 2;                          // comp offset within half
  int pofs = tid >> 2;                              // 0..255

  for (int h = 0; h < 2; ++h) {
    __syncthreads();                                // readers of prev half done
    // stage: 6144 float4, coalesced global read, conflict-free b128 LDS write
    for (int u = tid; u < 3 * NR * 4; u += BLK) {
      int a = u >> 11;                              // axis (2048 float4/axis)
      int rem = u & 2047;
      const float* src = (a == 0) ? tx : (a == 1) ? ty : tz;
      float4 v = *(const float4*)(src + (h << 13) + (rem << 2));
      *(float4*)(&lds[(a << 13) + (rem << 2)]) = v;
    }
    if (h == 0 && tid < HC) lds[3 * NR * HC + tid] = 0.0f;  // zero guard row
    __syncthreads();

    int p = base_p + pofs;
    int pc = min(p, npts - 1);
    float x = pos[3 * pc], y = pos[3 * pc + 1], z = pos[3 * pc + 2];

    for (int it = 0; it < iters; ++it) {
      int pn = p + (BLK / 4);
      float xn = 0.f, yn = 0.f, zn = 0.f;
      if (it + 1 < iters) {                         // prefetch next iter's pos
        int pcn = min(pn, npts - 1);
        xn = pos[3 * pcn];
        yn = pos[3 * pcn + 1];
        zn = pos[3 * pcn + 2];
      }
      float4 fx = lerp4(lds, x, j4);
      float4 fy = lerp4(lds + (NR * HC), y, j4);
      float4 fz = lerp4(lds + 2 * (NR * HC), z, j4);
      float4 r;
      r.x = fx.x * fy.x * fz.x;
      r.y = fx.y * fy.y * fz.y;
      r.z = fx.z * fy.z * fz.z;
      r.w = fx.w * fy.w * fz.w;
      if (p < pend)
        *(float4*)(out + (size_t)p * NC + h * HC + j4) = r;
      p = pn; x = xn; y = yn; z = zn;
    }
  }
}

// ---------------------------------------------------------------------------
// Fallback (ws too small): original untransposed path, 8 threads/point.
// ---------------------------------------------------------------------------
__device__ __forceinline__ float4 sample4_u(const float* __restrict__ t,
                                            float x, int c4) {
  float ix = (x + 1.0f) * 0.5f * (float)(NR - 1);
  float f = floorf(ix);
  float w = ix - f;
  int i0 = (int)f;
  int i1 = i0 + 1;
  float m0 = (i0 >= 0 && i0 < NR) ? (1.0f - w) : 0.0f;
  float m1 = (i1 >= 0 && i1 < NR) ? w : 0.0f;
  int ci0 = min(max(i0, 0), NR - 1);
  int ci1 = min(max(i1, 0), NR - 1);
  float4 r;
  float* rp = (float*)&r;
  for (int j = 0; j < 4; ++j) {
    float v0 = t[(c4 + j) * NR + ci0];
    float v1 = t[(c4 + j) * NR + ci1];
    rp[j] = v0 * m0 + v1 * m1;
  }
  return r;
}

__global__ __launch_bounds__(256) void cp_encode_global(
    const float* __restrict__ pos, const float* __restrict__ vx,
    const float* __restrict__ vy, const float* __restrict__ vz,
    float* __restrict__ out, int npts) {
  int t = blockIdx.x * 256 + threadIdx.x;
  int p = t >> 3;
  if (p >= npts) return;
  int c4 = (t & 7) * 4;
  float x = pos[3 * p + 0];
  float y = pos[3 * p + 1];
  float z = pos[3 * p + 2];
  float4 fx = sample4_u(vx, x, c4);
  float4 fy = sample4_u(vy, y, c4);
  float4 fz = sample4_u(vz, z, c4);
  float4 r;
  r.x = fx.x * fy.x * fz.x;
  r.y = fx.y * fy.y * fz.y;
  r.z = fx.z * fy.z * fz.z;
  r.w = fx.w * fy.w * fz.w;
  *(float4*)(out + (long long)p * NC + c4) = r;
}

extern "C" void kernel_launch(void* const* d_in, const int* in_sizes, int n_in,
                              void* d_out, int out_size, void* d_ws,
                              size_t ws_size, hipStream_t stream) {
  const float* pos = (const float*)d_in[0];
  const float* vx = (const float*)d_in[1];
  const float* vy = (const float*)d_in[2];
  const float* vz = (const float*)d_in[3];
  float* out = (float*)d_out;
  int npts = in_sizes[0] / 3;

  const size_t tbytes = (size_t)3 * NC * NR * sizeof(float);  // 192 KiB

  if (ws_size >= tbytes) {
    static int lds_attr_set = 0;
    if (!lds_attr_set) {
      hipFuncSetAttribute((const void*)cp_encode_lds,
                          hipFuncAttributeMaxDynamicSharedMemorySize,
                          LDS_BYTES);
      lds_attr_set = 1;
    }
    float* tx = (float*)d_ws;
    float* ty = tx + NC * NR;
    float* tz = ty + NC * NR;
    int tb = (3 * NC * NR + 255) / 256;
    transpose_vecs<<<tb, 256, 0, stream>>>(vx, vy, vz, tx, ty, tz);
    int chunk_pts = (npts + NCHUNK - 1) / NCHUNK;
    cp_encode_lds<<<NCHUNK, BLK, LDS_BYTES, stream>>>(pos, tx, ty, tz, out,
                                                      npts, chunk_pts);
  } else {
    int blocks = (npts * 8 + 255) / 256;
    cp_encode_global<<<blocks, 256, 0, stream>>>(pos, vx, vy, vz, out, npts);
  }
}

// Round 2
// 318.159 us; speedup vs baseline: 1.1247x; 1.1247x over previous
//
#include <hip/hip_runtime.h>

#define NC 32
#define NR 512
#define HC 16                 // components per half-pass
#define BLK 1024
#define PPB 1024              // points per block
#define ITERS 4               // PPB / (BLK/4 points per iter)

// LDS: 3 axes * 512 rows * 16 comps fp32 = 96 KiB (no guard row needed:
// i0 is clamped to <= 510 so i1 <= 511 is always in-table).
#define LDS_FLOATS (3 * NR * HC)
#define LDS_BYTES (LDS_FLOATS * 4)

// ---------------------------------------------------------------------------
// Kernel 1: transpose the three [C=32, R=512] tables into half-split
// [h][R=512][16] layout in ws: dst[(c>>4)*8192 + r*16 + (c&15)] = src[c*512+r]
// ---------------------------------------------------------------------------
__global__ __launch_bounds__(256) void transpose_vecs(
    const float* __restrict__ vx, const float* __restrict__ vy,
    const float* __restrict__ vz, float* __restrict__ tx,
    float* __restrict__ ty, float* __restrict__ tz) {
  int u = blockIdx.x * 256 + threadIdx.x;           // 0 .. 3*16384-1
  if (u >= 3 * NC * NR) return;
  int table = u >> 14;                              // /16384
  int e = u & (NC * NR - 1);                        // c*512 + r
  int c = e >> 9;
  int r = e & (NR - 1);
  const float* src = (table == 0) ? vx : (table == 1) ? vy : vz;
  float* dst = (table == 0) ? tx : (table == 1) ? ty : tz;
  dst[((c >> 4) << 13) + (r << 4) + (c & (HC - 1))] = src[e];
}

// ---------------------------------------------------------------------------
// In-LDS 1D lerp, 4 components from a [512][16] table half.
// grid_sample(align_corners=True) semantics; i0 clamped to 510 so the i1 row
// is always valid (at ix==511 exactly, w==1 puts full weight on row 511 --
// identical to reference output for x in [-1, 1]).
// ---------------------------------------------------------------------------
__device__ __forceinline__ float4 lerp4(const float* __restrict__ t,
                                        float x, int j4) {
  float ix = fmaf(x, 0.5f * (NR - 1), 0.5f * (NR - 1));
  ix = fminf(fmaxf(ix, 0.0f), (float)(NR - 1));
  float f = fminf(floorf(ix), (float)(NR - 2));
  float w = ix - f;
  int i0 = (int)f;
  const float* a = t + (i0 << 4) + j4;
  float4 v0 = *(const float4*)a;
  float4 v1 = *(const float4*)(a + HC);             // row i0+1 = +64 B
  float4 r;
  r.x = fmaf(w, v1.x - v0.x, v0.x);
  r.y = fmaf(w, v1.y - v0.y, v0.y);
  r.z = fmaf(w, v1.z - v0.z, v0.z);
  r.w = fmaf(w, v1.w - v0.w, v0.w);
  return r;
}

// ---------------------------------------------------------------------------
// Kernel 2: one 1024-thread block owns 1024 points. Two passes:
//   h=0: stage comps 0-15 (96 KiB) -> compute -> KEEP RESULTS IN REGISTERS
//   h=1: stage comps 16-31 -> compute -> store BOTH halves back-to-back
// so every 128-B output line is fully dirtied in one window (no L2
// partial-line write-allocate RMW). 4 threads/point, ds_read_b128 table reads.
// ---------------------------------------------------------------------------
__global__ __launch_bounds__(BLK, 4) void cp_encode_lds(
    const float* __restrict__ pos, const float* __restrict__ tx,
    const float* __restrict__ ty, const float* __restrict__ tz,
    float* __restrict__ out, int npts) {
  extern __shared__ float lds[];
  int tid = threadIdx.x;
  int base_p = blockIdx.x * PPB;
  int j4 = (tid & 3) << 2;                          // comp quad within half
  int pofs = tid >> 2;                              // 0..255

  // Load positions once; reused by both passes.
  float xs[ITERS], ys[ITERS], zs[ITERS];
  float4 r0[ITERS];
#pragma unroll
  for (int it = 0; it < ITERS; ++it) {
    int p = base_p + pofs + it * (BLK / 4);
    int pc = min(p, npts - 1);
    xs[it] = pos[3 * pc + 0];
    ys[it] = pos[3 * pc + 1];
    zs[it] = pos[3 * pc + 2];
  }

  for (int h = 0; h < 2; ++h) {
    __syncthreads();                                // prev-pass readers done
    // stage: 6144 float4 = 6 per thread, coalesced global, linear LDS write
    for (int u = tid; u < 3 * NR * 4; u += BLK) {
      int a = u >> 11;                              // axis (2048 float4/axis)
      int rem = u & 2047;
      const float* src = (a == 0) ? tx : (a == 1) ? ty : tz;
      *(float4*)(&lds[(a << 13) + (rem << 2)]) =
          *(const float4*)(src + (h << 13) + (rem << 2));
    }
    __syncthreads();

#pragma unroll
    for (int it = 0; it < ITERS; ++it) {
      float4 fx = lerp4(lds, xs[it], j4);
      float4 fy = lerp4(lds + (NR * HC), ys[it], j4);
      float4 fz = lerp4(lds + 2 * (NR * HC), zs[it], j4);
      float4 r;
      r.x = fx.x * fy.x * fz.x;
      r.y = fx.y * fy.y * fz.y;
      r.z = fx.z * fy.z * fz.z;
      r.w = fx.w * fy.w * fz.w;
      if (h == 0) {
        r0[it] = r;
      } else {
        int p = base_p + pofs + it * (BLK / 4);
        if (p < npts) {
          float* o = out + (size_t)p * NC;
          *(float4*)(o + j4) = r0[it];              // comps 0-15 half
          *(float4*)(o + HC + j4) = r;              // comps 16-31 half
        }
      }
    }
  }
}

// ---------------------------------------------------------------------------
// Fallback (ws too small): untransposed scattered-read path, 8 threads/point.
// ---------------------------------------------------------------------------
__device__ __forceinline__ float4 sample4_u(const float* __restrict__ t,
                                            float x, int c4) {
  float ix = (x + 1.0f) * 0.5f * (float)(NR - 1);
  float f = floorf(ix);
  float w = ix - f;
  int i0 = (int)f;
  int i1 = i0 + 1;
  float m0 = (i0 >= 0 && i0 < NR) ? (1.0f - w) : 0.0f;
  float m1 = (i1 >= 0 && i1 < NR) ? w : 0.0f;
  int ci0 = min(max(i0, 0), NR - 1);
  int ci1 = min(max(i1, 0), NR - 1);
  float4 r;
  float* rp = (float*)&r;
  for (int j = 0; j < 4; ++j) {
    float v0 = t[(c4 + j) * NR + ci0];
    float v1 = t[(c4 + j) * NR + ci1];
    rp[j] = v0 * m0 + v1 * m1;
  }
  return r;
}

__global__ __launch_bounds__(256) void cp_encode_global(
    const float* __restrict__ pos, const float* __restrict__ vx,
    const float* __restrict__ vy, const float* __restrict__ vz,
    float* __restrict__ out, int npts) {
  int t = blockIdx.x * 256 + threadIdx.x;
  int p = t >> 3;
  if (p >= npts) return;
  int c4 = (t & 7) * 4;
  float x = pos[3 * p + 0];
  float y = pos[3 * p + 1];
  float z = pos[3 * p + 2];
  float4 fx = sample4_u(vx, x, c4);
  float4 fy = sample4_u(vy, y, c4);
  float4 fz = sample4_u(vz, z, c4);
  float4 r;
  r.x = fx.x * fy.x * fz.x;
  r.y = fx.y * fy.y * fz.y;
  r.z = fx.z * fy.z * fz.z;
  r.w = fx.w * fy.w * fz.w;
  *(float4*)(out + (long long)p * NC + c4) = r;
}

extern "C" void kernel_launch(void* const* d_in, const int* in_sizes, int n_in,
                              void* d_out, int out_size, void* d_ws,
                              size_t ws_size, hipStream_t stream) {
  const float* pos = (const float*)d_in[0];
  const float* vx = (const float*)d_in[1];
  const float* vy = (const float*)d_in[2];
  const float* vz = (const float*)d_in[3];
  float* out = (float*)d_out;
  int npts = in_sizes[0] / 3;

  const size_t tbytes = (size_t)3 * NC * NR * sizeof(float);  // 192 KiB

  if (ws_size >= tbytes) {
    static int lds_attr_set = 0;
    if (!lds_attr_set) {
      hipFuncSetAttribute((const void*)cp_encode_lds,
                          hipFuncAttributeMaxDynamicSharedMemorySize,
                          LDS_BYTES);
      lds_attr_set = 1;
    }
    float* tx = (float*)d_ws;
    float* ty = tx + NC * NR;
    float* tz = ty + NC * NR;
    int tb = (3 * NC * NR + 255) / 256;
    transpose_vecs<<<tb, 256, 0, stream>>>(vx, vy, vz, tx, ty, tz);
    int blocks = (npts + PPB - 1) / PPB;
    cp_encode_lds<<<blocks, BLK, LDS_BYTES, stream>>>(pos, tx, ty, tz, out,
                                                      npts);
  } else {
    int blocks = (npts * 8 + 255) / 256;
    cp_encode_global<<<blocks, 256, 0, stream>>>(pos, vx, vy, vz, out, npts);
  }
}